// Round 18
// baseline (6969.822 us; speedup 1.0000x reference)
//
#include <hip/hip_runtime.h>

#define N_EXC  512
#define NTOT   640
#define NIN    16
#define BATCH  64
#define TSTEPS 1000
#define CHUNK  80       // units per block (8 chunk-groups)
#define THREADS 1024
#define NPT    10       // n per thread (8 ti-groups * 10 = 80)
#define KPT    5        // k per thread (128 tj-groups * 5 = 640)
#define RBUF_BYTES (2 * BATCH * NTOT * 4)   // 327680
// ALPHA = 0.5, NOISE_SCALE = 0.01

typedef float    f32x2 __attribute__((ext_vector_type(2)));
typedef unsigned u32x4 __attribute__((ext_vector_type(4)));
typedef unsigned u32x2 __attribute__((ext_vector_type(2)));

// ---------------------------------------------------------------------------
// JAX threefry2x32, key = jax.random.key(42) -> (0, 42); partitionable bits
// ---------------------------------------------------------------------------
__device__ __forceinline__ void threefry_0_42(unsigned x0, unsigned x1,
                                              unsigned& o0, unsigned& o1) {
    const unsigned ks1 = 42u;
    const unsigned ks2 = 0x1BD11BDAu ^ 42u;
    x0 += 0u; x1 += ks1;
#define TF_RND(r) { x0 += x1; x1 = (x1 << (r)) | (x1 >> (32 - (r))); x1 ^= x0; }
    TF_RND(13) TF_RND(15) TF_RND(26) TF_RND(6)
    x0 += ks1; x1 += ks2 + 1u;
    TF_RND(17) TF_RND(29) TF_RND(16) TF_RND(24)
    x0 += ks2; x1 += 0u + 2u;
    TF_RND(13) TF_RND(15) TF_RND(26) TF_RND(6)
    x0 += 0u; x1 += ks1 + 3u;
    TF_RND(17) TF_RND(29) TF_RND(16) TF_RND(24)
    x0 += ks1; x1 += ks2 + 4u;
    TF_RND(13) TF_RND(15) TF_RND(26) TF_RND(6)
    x0 += ks2; x1 += 0u + 5u;
#undef TF_RND
    o0 = x0; o1 = x1;
}

__device__ __forceinline__ unsigned jax_bits_partitionable(unsigned idx) {
    unsigned o0, o1;
    threefry_0_42(0u, idx, o0, o1);
    return o0 ^ o1;
}

// bits -> jax.random.normal sample scaled by NOISE_SCALE*sqrt(ALPHA), f32-exact
__device__ __forceinline__ float noise_from_bits(unsigned bits) {
    float f = __uint_as_float(0x3f800000u | (bits >> 9)) - 1.0f;   // [0,1)
    float u = __fadd_rn(__fmul_rn(f, 2.0f), -0.99999994f);
    u = fmaxf(-0.99999994f, u);
    float w = -log1pf(-__fmul_rn(u, u));
    float p;
    if (w < 5.0f) {
        float ww = w - 2.5f;
        p = 2.81022636e-08f;
        p = fmaf(p, ww, 3.43273939e-07f);
        p = fmaf(p, ww, -3.5233877e-06f);
        p = fmaf(p, ww, -4.39150654e-06f);
        p = fmaf(p, ww, 0.00021858087f);
        p = fmaf(p, ww, -0.00125372503f);
        p = fmaf(p, ww, -0.00417768164f);
        p = fmaf(p, ww, 0.246640727f);
        p = fmaf(p, ww, 1.50140941f);
    } else {
        float ww = sqrtf(w) - 3.0f;
        p = -0.000200214257f;
        p = fmaf(p, ww, 0.000100950558f);
        p = fmaf(p, ww, 0.00134934322f);
        p = fmaf(p, ww, -0.00367342844f);
        p = fmaf(p, ww, 0.00573950773f);
        p = fmaf(p, ww, -0.0076224613f);
        p = fmaf(p, ww, 0.00943887047f);
        p = fmaf(p, ww, 1.00167406f);
        p = fmaf(p, ww, 2.83297682f);
    }
    float z = 1.41421354f * (p * u);
    return (0.01f * 0.70710677f) * z;
}

// round-to-nearest-even bf16 (low 16 bits of result)
__device__ __forceinline__ unsigned rne_bf16(float f) {
    unsigned u = __float_as_uint(f);
    return (u + 0x7FFFu + ((u >> 16) & 1u)) >> 16;
}

// dale-transformed weights for units (n0,n1) at input k, bf16-packed lo|hi<<16
__device__ __forceinline__ unsigned packw2(const float* __restrict__ W,
                                           int n0, int n1, int k, float sg) {
    float lo = fabsf(W[(size_t)n0 * NTOT + k]) * sg; if (n0 == k) lo = 0.f;
    float hi = fabsf(W[(size_t)n1 * NTOT + k]) * sg; if (n1 == k) hi = 0.f;
    return rne_bf16(lo) | (rne_bf16(hi) << 16);
}

// packed u32 -> f32x2 (bf16 lo/hi widened exactly)
__device__ __forceinline__ f32x2 uf2(unsigned u) {
    u32x2 t = {u << 16, u & 0xFFFF0000u};
    return __builtin_bit_cast(f32x2, t);
}

#define FOR5(M) M(0) M(1) M(2) M(3) M(4)

// ---------------------------------------------------------------------------
// Persistent kernel: 256 blocks x 1024 threads, 1 WG/CU (the only residency
// pattern that has ever worked: r4-r14). Block B: chunk g=B>>5 (CHUNK=80) of
// batches bb=B&31 and bb+32 (shared weight unpack, 2x work per sync round).
// DEADLOCK ROOT-CAUSE FIX (r15/r16/r17 all hung on the same bug): publish and
// poll were in if/ELSE branches of one divergent conditional; if the compiler
// orders the poll branch first, mixed waves block their own publishes behind
// the poll loop -> circular cross-block wait. r13/r14 (which worked) used
// SEQUENTIAL statements: publish-if, then poll-if. Restored here: program
// order guarantees every wave issues its publishes before any of its polls.
// Occupancy: ONE genuinely-used 84KB LDS array -> 1 WG/CU -> allocator
// targets 16 waves/CU -> VGPR cap 128 >= demand ~80 (25 weight u32 + 20 acc).
// Worst-case allocator surprise = spill, never lost residency.
// ---------------------------------------------------------------------------
__global__ __launch_bounds__(THREADS, 4)
void eirnn_sync(const float* __restrict__ inputs, const float* __restrict__ Wraw,
                const float* __restrict__ W_in, const float* __restrict__ W_out,
                const float* __restrict__ b_out, float* __restrict__ rates_out,
                float* __restrict__ outs_out, unsigned* __restrict__ rbuf) {
    const int bb  = blockIdx.x & 31;       // batch-pair id: batches bb, bb+32
    const int g   = blockIdx.x >> 5;       // chunk 0..7
    const int tid = threadIdx.x;
    const int ti  = tid & 7;               // n-group (0..7)
    const int tj  = tid >> 3;              // k-group (0..127)
    const int wv  = tid >> 6;              // wave (0..15)
    const int nbase = g * CHUNK;
    const int nloc  = nbase + ti * NPT;    // first owned n (global id)
    const int kbase = tj * KPT;            // first owned k

    // single used LDS block: 21504 floats = 84KB -> forces 1 WG/CU (cap 128)
    __shared__ __align__(16) float smem[21504];
    float*    r_all = smem;                         // [2][2][640]
    float*    part  = smem + 2560;                  // [16][2][80]
    unsigned* win_s = (unsigned*)(smem + 5120);     // [80][9] packed bf16x2
    float*    u_s   = smem + 5840;                  // [2][2][16]
    float*    red0  = smem + 5904;                  // [16]
    float*    red1  = smem + 5920;                  // [16]
    float*    bo_s  = smem + 5936;                  // [2]

    // ---- named packed-bf16 weight registers: 5 k-slots x 5 n-pairs --------
#define DECLW(K) u32x4 wA##K; unsigned wB##K;
    FOR5(DECLW)
#undef DECLW

#define LOADW(K) {                                                          \
        const int k_ = kbase + (K);                                         \
        const float sg_ = (k_ < N_EXC) ? 1.f : -1.f;                        \
        wA##K = (u32x4){packw2(Wraw, nloc + 0, nloc + 1, k_, sg_),          \
                        packw2(Wraw, nloc + 2, nloc + 3, k_, sg_),          \
                        packw2(Wraw, nloc + 4, nloc + 5, k_, sg_),          \
                        packw2(Wraw, nloc + 6, nloc + 7, k_, sg_)};         \
        wB##K = packw2(Wraw, nloc + 8, nloc + 9, k_, sg_);                  \
    }
    FOR5(LOADW)
#undef LOADW

    // W_in chunk -> LDS as bf16x2 (stride 9, odd -> conflict-free)
    for (int i = tid; i < CHUNK * 8; i += THREADS) {
        int o = i >> 3, j = i & 7;
        float a0 = W_in[(nbase + o) * NIN + 2 * j];
        float a1 = W_in[(nbase + o) * NIN + 2 * j + 1];
        win_s[o * 9 + j] = rne_bf16(a0) | (rne_bf16(a1) << 16);
    }
    // readout weights: g==0; tid&511 spans exactly r[:512]; tid>>9 = batch
    float wo0 = 0.0f, wo1 = 0.0f;
    if (g == 0) { wo0 = W_out[tid & 511]; wo1 = W_out[N_EXC + (tid & 511)]; }
    if (tid < 2) bo_s[tid] = b_out[tid];

    // owner role: tid < 160 owns (bt_own, o_own)
    const int bt_own = (tid >= CHUNK) ? 1 : 0;     // valid for tid<160
    const int o_own  = tid - bt_own * CHUNK;
    const int batch_own = bb + bt_own * 32;
    const float* inp0 = inputs + (size_t)bb * TSTEPS * NIN;
    const float* inp1 = inputs + (size_t)(bb + 32) * TSTEPS * NIN;
    float* rates_own = rates_out + (size_t)batch_own * TSTEPS * NTOT + nbase + o_own;
    float* outs_b0 = outs_out + (size_t)bb * TSTEPS * 2;
    float* outs_b1 = outs_out + (size_t)(bb + 32) * TSTEPS * 2;

    // poller role: tid in [160,1024) -> 864 pollers cover 1120 remote words
    int w1bt = 0, w1off = 0, w2off = -1;
    if (tid >= 2 * CHUNK) {
        const int pidx = tid - 2 * CHUNK;          // 0..863
        w1bt = (pidx >= 560) ? 1 : 0;
        int rw = pidx - w1bt * 560;
        int p = rw / CHUNK;
        int gg = p + (p >= g ? 1 : 0);
        w1off = gg * CHUNK + (rw - p * CHUNK);
        if (pidx < 256) {                          // second word (batch 1)
            int rw2 = 864 + pidx - 560;            // 304..559
            int p2 = rw2 / CHUNK;
            int gg2 = p2 + (p2 >= g ? 1 : 0);
            w2off = gg2 * CHUNK + (rw2 - p2 * CHUNK);
        }
    }

    // prologue: u for t=0 (32 loader threads, 2 batches x 16)
    if (tid >= THREADS - 32) {
        int j = tid - (THREADS - 32);
        int ubt = j >> 4, uj = j & 15;
        u_s[ubt * 16 + uj] = (ubt ? inp1 : inp0)[uj];
    }

    float x = 0.0f;   // owner state for tid < 160
    __syncthreads();  // weights/win_s/bo_s/u_s ready

    for (int t = 0; t < TSTEPS; ++t) {
        const int buf = t & 1;
        const unsigned tagv = (unsigned)(t & 3);
        unsigned* rb0 = rbuf + (size_t)(buf * BATCH + bb) * NTOT;
        unsigned* rb1 = rbuf + (size_t)(buf * BATCH + bb + 32) * NTOT;
        float* raw = r_all + buf * 2 * NTOT;       // [2][640] this parity

        // ---- phase A, statement 1: ALL owners publish (program order first)
        float r_exact = 0.0f;
        if (tid < 2 * CHUNK) {
            r_exact = fmaxf(x, 0.0f) + log1pf(expf(-fabsf(x)));
            unsigned rbits = (__float_as_uint(r_exact) & ~3u) | tagv;
            raw[bt_own * NTOT + nbase + o_own] = __uint_as_float(rbits);
            __hip_atomic_store((bt_own ? rb1 : rb0) + nbase + o_own, rbits,
                               __ATOMIC_RELAXED, __HIP_MEMORY_SCOPE_AGENT);
        }
        // ---- phase A, statement 2: pollers pull remote (publishes already
        //      issued by every wave before any poll -- no circular wait)
        if (tid >= 2 * CHUNK) {
            const unsigned* s1 = (w1bt ? rb1 : rb0) + w1off;
            unsigned w;
            do {
                w = __hip_atomic_load(s1, __ATOMIC_RELAXED,
                                      __HIP_MEMORY_SCOPE_AGENT);
            } while (((w & 3u) != tagv) || ((int)w <= 0x00800000));
            raw[w1bt * NTOT + w1off] = __uint_as_float(w);
            if (w2off >= 0) {
                const unsigned* s2 = rb1 + w2off;
                do {
                    w = __hip_atomic_load(s2, __ATOMIC_RELAXED,
                                          __HIP_MEMORY_SCOPE_AGENT);
                } while (((w & 3u) != tagv) || ((int)w <= 0x00800000));
                raw[NTOT + w2off] = __uint_as_float(w);
            }
        }
        __syncthreads();   // b1: both batches' r complete in LDS

        // deferred HBM work: drains under the GEMV, not at a barrier
        if (tid < 2 * CHUNK) rates_own[t * NTOT] = r_exact;
        if (tid >= THREADS - 32 && t + 1 < TSTEPS) {
            int j = tid - (THREADS - 32);
            int ubt = j >> 4, uj = j & 15;
            u_s[(((t + 1) & 1) * 2 + ubt) * 16 + uj] =
                (ubt ? inp1 : inp0)[(t + 1) * NIN + uj];
        }
        // eps precompute: threefry chain overlaps GEMV
        float eps = 0.0f;
        if (tid < 2 * CHUNK) {
            unsigned idx = (unsigned)(t * (BATCH * NTOT) + batch_own * NTOT
                                      + nbase + o_own);
            eps = noise_from_bits(jax_bits_partitionable(idx));
        }

        // ---- phase C: register GEMV for BOTH batches (shared unpack) -------
        {
            const float* ra0 = raw;
            const float* ra1 = raw + NTOT;
            f32x2 b0a0 = {0.f,0.f}, b0a1 = {0.f,0.f}, b0a2 = {0.f,0.f};
            f32x2 b0a3 = {0.f,0.f}, b0a4 = {0.f,0.f};
            f32x2 b1a0 = {0.f,0.f}, b1a1 = {0.f,0.f}, b1a2 = {0.f,0.f};
            f32x2 b1a3 = {0.f,0.f}, b1a4 = {0.f,0.f};
#define FMAK(K) { const float rk0 = ra0[kbase + (K)];                       \
                  const float rk1 = ra1[kbase + (K)];                       \
                  { f32x2 w_ = uf2(wA##K.x); b0a0 += w_*rk0; b1a0 += w_*rk1; } \
                  { f32x2 w_ = uf2(wA##K.y); b0a1 += w_*rk0; b1a1 += w_*rk1; } \
                  { f32x2 w_ = uf2(wA##K.z); b0a2 += w_*rk0; b1a2 += w_*rk1; } \
                  { f32x2 w_ = uf2(wA##K.w); b0a3 += w_*rk0; b1a3 += w_*rk1; } \
                  { f32x2 w_ = uf2(wB##K);   b0a4 += w_*rk0; b1a4 += w_*rk1; } }
            FOR5(FMAK)
#undef FMAK
            // reduce over the 8 tj-groups inside this wave (lane bits 3,4,5)
#define WRED(S) { S.x += __shfl_xor(S.x, 8); S.x += __shfl_xor(S.x, 16);    \
                  S.x += __shfl_xor(S.x, 32);                               \
                  S.y += __shfl_xor(S.y, 8); S.y += __shfl_xor(S.y, 16);    \
                  S.y += __shfl_xor(S.y, 32); }
            WRED(b0a0) WRED(b0a1) WRED(b0a2) WRED(b0a3) WRED(b0a4)
            WRED(b1a0) WRED(b1a1) WRED(b1a2) WRED(b1a3) WRED(b1a4)
#undef WRED
            if ((tid & 63) < 8) {              // lane == ti
                float* p0 = part + (wv * 2 + 0) * CHUNK + (tid & 7) * NPT;
                *(f32x2*)(p0 + 0) = b0a0; *(f32x2*)(p0 + 2) = b0a1;
                *(f32x2*)(p0 + 4) = b0a2; *(f32x2*)(p0 + 6) = b0a3;
                *(f32x2*)(p0 + 8) = b0a4;
                float* p1 = part + (wv * 2 + 1) * CHUNK + (tid & 7) * NPT;
                *(f32x2*)(p1 + 0) = b1a0; *(f32x2*)(p1 + 2) = b1a1;
                *(f32x2*)(p1 + 4) = b1a2; *(f32x2*)(p1 + 6) = b1a3;
                *(f32x2*)(p1 + 8) = b1a4;
            }
            // readout partials on g==0: waves 0-7 batch0, waves 8-15 batch1
            if (g == 0) {
                float rr = raw[(tid >> 9) * NTOT + (tid & 511)];
                float p0 = rr * wo0, p1 = rr * wo1;
#pragma unroll
                for (int off = 32; off; off >>= 1) {
                    p0 += __shfl_down(p0, off);
                    p1 += __shfl_down(p1, off);
                }
                if ((tid & 63) == 0) { red0[wv] = p0; red1[wv] = p1; }
            }
        }
        __syncthreads();   // b2: part/red ready

        // ---- phase D: owner state update (no trailing barrier) -------------
        if (tid < 2 * CHUNK) {
            float rec = 0.0f;
#pragma unroll
            for (int j = 0; j < 16; ++j)
                rec += part[(j * 2 + bt_own) * CHUNK + o_own];
            const float* ub = u_s + (buf * 2 + bt_own) * 16;
            float ext = 0.0f;
#pragma unroll
            for (int j = 0; j < 8; ++j) {
                f32x2 wj = uf2(win_s[o_own * 9 + j]);
                ext = fmaf(wj.x, ub[2 * j], fmaf(wj.y, ub[2 * j + 1], ext));
            }
            x = (0.5f * x + 0.5f * (rec + ext)) + eps;
        }
        if (g == 0 && tid == 0) {
            float y0 = bo_s[0], y1 = bo_s[1];
#pragma unroll
            for (int k = 0; k < 8; ++k) { y0 += red0[k]; y1 += red1[k]; }
            outs_b0[t * 2 + 0] = y0;
            outs_b0[t * 2 + 1] = y1;
        }
        if (g == 0 && tid == 512) {
            float y0 = bo_s[0], y1 = bo_s[1];
#pragma unroll
            for (int k = 8; k < 16; ++k) { y0 += red0[k]; y1 += red1[k]; }
            outs_b1[t * 2 + 0] = y0;
            outs_b1[t * 2 + 1] = y1;
        }
        // next iteration's writes are fenced by next barriers (parity buffers)
    }
}

// ---------------------------------------------------------------------------
extern "C" void kernel_launch(void* const* d_in, const int* in_sizes, int n_in,
                              void* d_out, int out_size, void* d_ws, size_t ws_size,
                              hipStream_t stream) {
    const float* inputs = (const float*)d_in[0];   // [64,1000,16]
    const float* Wraw   = (const float*)d_in[1];   // [640,640]
    const float* W_in   = (const float*)d_in[2];   // [640,16]
    const float* W_out  = (const float*)d_in[3];   // [2,512]
    const float* b_out  = (const float*)d_in[4];   // [2]

    float* out   = (float*)d_out;
    float* rates = out;                                    // [64,1000,640]
    float* outs  = out + (size_t)BATCH * TSTEPS * NTOT;    // [64,1000,2]

    unsigned* rbuf = (unsigned*)d_ws;   // [2][64][640] u32 (tagged rates)

    // sentinel-fill each call (0xAAAAAAAA: negative & tag=2 -> rejected at
    // t=0 (tag 0) and t=1 (tag 1); in-graph so every replay is identical)
    hipMemsetAsync(d_ws, 0xAA, RBUF_BYTES, stream);
    eirnn_sync<<<dim3(256), dim3(THREADS), 0, stream>>>(
        inputs, Wraw, W_in, W_out, b_out, rates, outs, rbuf);
}